// Round 11
// baseline (139.901 us; speedup 1.0000x reference)
//
#include <hip/hip_runtime.h>
#include <math.h>

#define DD 128
#define SLOT 64   // fixed CSR bucket stride; deg~Poisson(12.8), P(>64) ~ 0

__device__ __forceinline__ unsigned bf16rne(float f) {
    unsigned u = __float_as_uint(f);
    return (u + 0x7FFFu + ((u >> 16) & 1u)) >> 16;
}
__device__ __forceinline__ float2 bf2f(unsigned u) {
    float2 r;
    r.x = __uint_as_float(u << 16);
    r.y = __uint_as_float(u & 0xFFFF0000u);
    return r;
}

// ---- mark live nodes into a BITMASK (6.25 KB -> L1-resident) ---------------
__global__ __launch_bounds__(256) void k_mark(const int* __restrict__ src1,
                                              const int* __restrict__ dst1,
                                              int E1, int BS,
                                              unsigned* __restrict__ mb) {
    int base = blockIdx.x * 1024 + threadIdx.x;
    #pragma unroll
    for (int j = 0; j < 4; ++j) {
        int e = base + j * 256;
        if (e < E1) {
            int d = dst1[e];
            if (d < BS) {
                int s = src1[e];
                atomicOr(&mb[s >> 5], 1u << (s & 31));
            }
        }
    }
    int g = blockIdx.x * 256 + threadIdx.x;
    if (g < BS) atomicOr(&mb[g >> 5], 1u << (g & 31));
}

// ---- F1: linear0 (64-row, prefetch-staged w) || hist+fill both convs || mscanA
__global__ __launch_bounds__(256) void k_hflin(
        const float* __restrict__ x, const float* __restrict__ w,
        const float* __restrict__ b, unsigned* __restrict__ y, int nrows,
        int gLin, int gH0, int gH1,
        const int* __restrict__ src0, const int* __restrict__ dst0, int E0,
        const int* __restrict__ src1, const int* __restrict__ dst1, int E1,
        int BS, const unsigned* __restrict__ mb, int* __restrict__ cnt,
        int* __restrict__ ssrc, int N,
        int W, int* __restrict__ mex, int* __restrict__ mbsum) {
    __shared__ float  xs[64][DD];     // 32 KB
    __shared__ float4 wb[32][32];     // 16 KB

    if (blockIdx.x >= gLin) {
        int role = blockIdx.x - gLin;
        if (role < gH0) {                       // hist+fill conv0 (live dst)
            int base = role * 1024 + threadIdx.x;
            #pragma unroll
            for (int j = 0; j < 4; ++j) {
                int e = base + j * 256;
                if (e < E0) {
                    int d = dst0[e];
                    if ((mb[d >> 5] >> (d & 31)) & 1u) {
                        int r = atomicAdd(&cnt[d], 1);
                        if (r < SLOT) ssrc[(size_t)d * SLOT + r] = src0[e];
                    }
                }
            }
        } else if (role < gH0 + gH1) {          // hist+fill conv1 (dst < BS)
            int base = (role - gH0) * 1024 + threadIdx.x;
            #pragma unroll
            for (int j = 0; j < 4; ++j) {
                int e = base + j * 256;
                if (e < E1) {
                    int d = dst1[e];
                    if (d < BS) {
                        int r = atomicAdd(&cnt[N + d], 1);
                        if (r < SLOT) ssrc[(size_t)(N + d) * SLOT + r] = src1[e];
                    }
                }
            }
        } else {                                // mscanA over mask words
            __shared__ int s[256];
            int idx = (role - gH0 - gH1) * 256 + threadIdx.x;
            int v = (idx < W) ? __popc(mb[idx]) : 0;
            s[threadIdx.x] = v;
            __syncthreads();
            for (int o = 1; o < 256; o <<= 1) {
                int t = (threadIdx.x >= o) ? s[threadIdx.x - o] : 0;
                __syncthreads();
                s[threadIdx.x] += t;
                __syncthreads();
            }
            if (idx < W) mex[idx] = s[threadIdx.x] - v;
            if (threadIdx.x == 255) mbsum[role - gH0 - gH1] = s[255];
        }
        return;
    }

    // ---- linear: 64 rows x 128 cols; w chunks prefetched into regs ----
    int rbase = blockIdx.x * 64;
    for (int i = threadIdx.x; i < 64 * 32; i += 256) {
        int r = rbase + (i >> 5);
        float4 v = make_float4(0.f, 0.f, 0.f, 0.f);
        if (r < nrows) v = ((const float4*)x)[(size_t)r * 32 + (i & 31)];
        *(float4*)&xs[i >> 5][(i & 31) * 4] = v;
    }
    const float4* wv = (const float4*)w;   // [k][32] float4
    {   // stage chunk 0
        float4* wf = &wb[0][0];
        #pragma unroll
        for (int i = 0; i < 4; ++i)
            wf[threadIdx.x + i * 256] = wv[threadIdx.x + i * 256];
    }
    __syncthreads();

    int g  = threadIdx.x >> 5;   // 8 groups of 32 lanes; group owns 8 rows
    int cg = threadIdx.x & 31;
    float4 bb = ((const float4*)b)[cg];
    float4 acc[8];
    #pragma unroll
    for (int r = 0; r < 8; ++r) acc[r] = bb;

    for (int c = 0; c < 4; ++c) {
        float4 pf0, pf1, pf2, pf3;
        if (c < 3) {               // issue next chunk's loads EARLY
            int gb = (c + 1) * 1024 + threadIdx.x;
            pf0 = wv[gb];       pf1 = wv[gb + 256];
            pf2 = wv[gb + 512]; pf3 = wv[gb + 768];
        }
        int kc = c * 32;
        #pragma unroll
        for (int kk = 0; kk < 32; kk += 4) {
            float4 wk0 = wb[kk][cg],     wk1 = wb[kk + 1][cg];
            float4 wk2 = wb[kk + 2][cg], wk3 = wb[kk + 3][cg];
            #pragma unroll
            for (int r = 0; r < 8; ++r) {
                float xr[4];
                *(float4*)xr = *(const float4*)&xs[g * 8 + r][kc + kk];
                acc[r].x += xr[0] * wk0.x; acc[r].y += xr[0] * wk0.y;
                acc[r].z += xr[0] * wk0.z; acc[r].w += xr[0] * wk0.w;
                acc[r].x += xr[1] * wk1.x; acc[r].y += xr[1] * wk1.y;
                acc[r].z += xr[1] * wk1.z; acc[r].w += xr[1] * wk1.w;
                acc[r].x += xr[2] * wk2.x; acc[r].y += xr[2] * wk2.y;
                acc[r].z += xr[2] * wk2.z; acc[r].w += xr[2] * wk2.w;
                acc[r].x += xr[3] * wk3.x; acc[r].y += xr[3] * wk3.y;
                acc[r].z += xr[3] * wk3.z; acc[r].w += xr[3] * wk3.w;
            }
        }
        if (c < 3) {
            __syncthreads();       // all waves done reading wb
            float4* wf = &wb[0][0];
            wf[threadIdx.x]       = pf0;
            wf[threadIdx.x + 256] = pf1;
            wf[threadIdx.x + 512] = pf2;
            wf[threadIdx.x + 768] = pf3;
            __syncthreads();       // writes visible
        }
    }
    #pragma unroll
    for (int r = 0; r < 8; ++r) {
        int row = rbase + g * 8 + r;
        if (row < nrows) {
            uint2 p;
            p.x = bf16rne(acc[r].x) | (bf16rne(acc[r].y) << 16);
            p.y = bf16rne(acc[r].z) | (bf16rne(acc[r].w) << 16);
            ((uint2*)y)[(size_t)row * 32 + cg] = p;
        }
    }
}

// ---- agg0 (mask-gated, all nodes) with leading livelist-build blocks -------
__global__ __launch_bounds__(256) void k_aggL(const unsigned* __restrict__ xl,
                                              const int* __restrict__ cnt,
                                              const int* __restrict__ ssrc,
                                              const float* __restrict__ att,
                                              const float* __restrict__ bias,
                                              float* __restrict__ out,
                                              const unsigned* __restrict__ mb,
                                              int n, int gMs, int W,
                                              const int* __restrict__ mex,
                                              const int* __restrict__ mbsum,
                                              int* __restrict__ livelist,
                                              int* __restrict__ nLive) {
    if (blockIdx.x < gMs) {
        // livelist compaction; per-block prefix over mbsum computed locally
        int pre = 0;
        for (int i = 0; i < (int)blockIdx.x; ++i) pre += mbsum[i];
        int idx = blockIdx.x * 256 + threadIdx.x;
        if (idx < W) {
            unsigned word = mb[idx];
            int base = mex[idx] + pre;
            unsigned wt = word;
            while (wt) {
                int bit = __ffs(wt) - 1;
                livelist[base + __popc(word & ((1u << bit) - 1u))] = idx * 32 + bit;
                wt &= wt - 1;
            }
            if (idx == W - 1) *nLive = base + __popc(word);
        }
        return;
    }
    int node = __builtin_amdgcn_readfirstlane((blockIdx.x - gMs) * 4 +
                                              (threadIdx.x >> 6));
    if (node >= n) return;
    if (!((mb[node >> 5] >> (node & 31)) & 1u)) return;
    int lane = threadIdx.x & 63;
    float2 attv = *(const float2*)&att[lane * 2];
    float2 xd = bf2f(xl[(size_t)node * 64 + lane]);
    int rs  = node * SLOT;
    int deg = cnt[node];
    deg = deg > SLOT ? SLOT : deg;

    float m = -3.4e38f, den = 0.f, accx = 0.f, accy = 0.f;
    int sA = (deg > 0) ? ssrc[rs] : 0;
    int sB = (deg > 1) ? ssrc[rs + 1] : 0;
    unsigned uA = xl[(size_t)sA * 64 + lane];
    unsigned uB = xl[(size_t)sB * 64 + lane];

    int k = 0;
    for (; k + 1 < deg; k += 2) {
        int sC = (k + 2 < deg) ? ssrc[rs + k + 2] : 0;
        int sD = (k + 3 < deg) ? ssrc[rs + k + 3] : 0;
        unsigned uC = xl[(size_t)sC * 64 + lane];
        unsigned uD = xl[(size_t)sD * 64 + lane];
        float2 vA = bf2f(uA), vB = bf2f(uB);

        float tx = xd.x + vA.x, ty = xd.y + vA.y;
        tx = tx > 0.f ? tx : 0.2f * tx;
        ty = ty > 0.f ? ty : 0.2f * ty;
        float l0 = tx * attv.x + ty * attv.y;
        tx = xd.x + vB.x; ty = xd.y + vB.y;
        tx = tx > 0.f ? tx : 0.2f * tx;
        ty = ty > 0.f ? ty : 0.2f * ty;
        float l1 = tx * attv.x + ty * attv.y;
        #pragma unroll
        for (int o = 8; o; o >>= 1) {
            l0 += __shfl_xor(l0, o, 64);
            l1 += __shfl_xor(l1, o, 64);
        }
        float mn = fmaxf(fmaxf(m, l0), l1);
        float corr = __expf(m - mn);
        float w0 = __expf(l0 - mn);
        float w1 = __expf(l1 - mn);
        den  = den  * corr + w0 + w1;
        accx = accx * corr + w0 * vA.x + w1 * vB.x;
        accy = accy * corr + w0 * vA.y + w1 * vB.y;
        m = mn;
        sA = sC; sB = sD; uA = uC; uB = uD;
    }
    if (k < deg) {
        float2 vA = bf2f(uA);
        float tx = xd.x + vA.x, ty = xd.y + vA.y;
        tx = tx > 0.f ? tx : 0.2f * tx;
        ty = ty > 0.f ? ty : 0.2f * ty;
        float l0 = tx * attv.x + ty * attv.y;
        #pragma unroll
        for (int o = 8; o; o >>= 1) l0 += __shfl_xor(l0, o, 64);
        float mn = fmaxf(m, l0);
        float corr = __expf(m - mn);
        float w0 = __expf(l0 - mn);
        den  = den  * corr + w0;
        accx = accx * corr + w0 * vA.x;
        accy = accy * corr + w0 * vA.y;
    }

    float inv = (deg > 0) ? 1.f / den : 0.f;
    float2 o2;
    o2.x = accx * inv + bias[lane * 2];
    o2.y = accy * inv + bias[lane * 2 + 1];
    *(float2*)&out[(size_t)node * DD + lane * 2] = o2;
}

// ---- lin1 over livelist rows (gelu on input, 64-row, prefetch-staged w) ----
__global__ __launch_bounds__(256) void k_linC(const float* __restrict__ x,
                                              const float* __restrict__ w,
                                              const float* __restrict__ b,
                                              unsigned* __restrict__ y,
                                              const int* __restrict__ livelist,
                                              const int* __restrict__ nLive) {
    __shared__ float  xs[64][DD];
    __shared__ float4 wb[32][32];
    int nL = *nLive;
    int lbase = blockIdx.x * 64;
    if (lbase >= nL) return;

    for (int i = threadIdx.x; i < 64 * 32; i += 256) {
        int li = lbase + (i >> 5);
        float4 v = make_float4(0.f, 0.f, 0.f, 0.f);
        if (li < nL) {
            int r = livelist[li];
            v = ((const float4*)x)[(size_t)r * 32 + (i & 31)];
            v.x = 0.5f * v.x * (1.f + erff(v.x * 0.70710678f));
            v.y = 0.5f * v.y * (1.f + erff(v.y * 0.70710678f));
            v.z = 0.5f * v.z * (1.f + erff(v.z * 0.70710678f));
            v.w = 0.5f * v.w * (1.f + erff(v.w * 0.70710678f));
        }
        *(float4*)&xs[i >> 5][(i & 31) * 4] = v;
    }
    const float4* wv = (const float4*)w;
    {
        float4* wf = &wb[0][0];
        #pragma unroll
        for (int i = 0; i < 4; ++i)
            wf[threadIdx.x + i * 256] = wv[threadIdx.x + i * 256];
    }
    __syncthreads();

    int g  = threadIdx.x >> 5;
    int cg = threadIdx.x & 31;
    float4 bb = ((const float4*)b)[cg];
    float4 acc[8];
    #pragma unroll
    for (int r = 0; r < 8; ++r) acc[r] = bb;

    for (int c = 0; c < 4; ++c) {
        float4 pf0, pf1, pf2, pf3;
        if (c < 3) {
            int gb = (c + 1) * 1024 + threadIdx.x;
            pf0 = wv[gb];       pf1 = wv[gb + 256];
            pf2 = wv[gb + 512]; pf3 = wv[gb + 768];
        }
        int kc = c * 32;
        #pragma unroll
        for (int kk = 0; kk < 32; kk += 4) {
            float4 wk0 = wb[kk][cg],     wk1 = wb[kk + 1][cg];
            float4 wk2 = wb[kk + 2][cg], wk3 = wb[kk + 3][cg];
            #pragma unroll
            for (int r = 0; r < 8; ++r) {
                float xr[4];
                *(float4*)xr = *(const float4*)&xs[g * 8 + r][kc + kk];
                acc[r].x += xr[0] * wk0.x; acc[r].y += xr[0] * wk0.y;
                acc[r].z += xr[0] * wk0.z; acc[r].w += xr[0] * wk0.w;
                acc[r].x += xr[1] * wk1.x; acc[r].y += xr[1] * wk1.y;
                acc[r].z += xr[1] * wk1.z; acc[r].w += xr[1] * wk1.w;
                acc[r].x += xr[2] * wk2.x; acc[r].y += xr[2] * wk2.y;
                acc[r].z += xr[2] * wk2.z; acc[r].w += xr[2] * wk2.w;
                acc[r].x += xr[3] * wk3.x; acc[r].y += xr[3] * wk3.y;
                acc[r].z += xr[3] * wk3.z; acc[r].w += xr[3] * wk3.w;
            }
        }
        if (c < 3) {
            __syncthreads();
            float4* wf = &wb[0][0];
            wf[threadIdx.x]       = pf0;
            wf[threadIdx.x + 256] = pf1;
            wf[threadIdx.x + 512] = pf2;
            wf[threadIdx.x + 768] = pf3;
            __syncthreads();
        }
    }
    #pragma unroll
    for (int r = 0; r < 8; ++r) {
        int li = lbase + g * 8 + r;
        if (li < nL) {
            int row = livelist[li];
            uint2 p;
            p.x = bf16rne(acc[r].x) | (bf16rne(acc[r].y) << 16);
            p.y = bf16rne(acc[r].z) | (bf16rne(acc[r].w) << 16);
            ((uint2*)y)[(size_t)row * 32 + cg] = p;
        }
    }
}

// ---- agg1 (nodes [0,BS)) fused with linear+LayerNorm head -------------------
__global__ __launch_bounds__(256) void k_agg1head(
        const unsigned* __restrict__ xl,
        const int* __restrict__ cnt, const int* __restrict__ ssrc,
        const float* __restrict__ att, const float* __restrict__ bias,
        const float* __restrict__ wout, const float* __restrict__ bout,
        const float* __restrict__ gamma, const float* __restrict__ beta,
        float* __restrict__ yout, int N, int BS) {
    __shared__ float xrow[4][DD];
    int wid  = threadIdx.x >> 6;
    int lane = threadIdx.x & 63;
    int node = blockIdx.x * 4 + wid;
    if (node >= BS) return;
    float2 attv = *(const float2*)&att[lane * 2];
    float2 xd = bf2f(xl[(size_t)node * 64 + lane]);
    int key = N + node;
    int rs  = key * SLOT;
    int deg = cnt[key];
    deg = deg > SLOT ? SLOT : deg;

    float m = -3.4e38f, den = 0.f, accx = 0.f, accy = 0.f;
    int sA = (deg > 0) ? ssrc[rs] : 0;
    int sB = (deg > 1) ? ssrc[rs + 1] : 0;
    unsigned uA = xl[(size_t)sA * 64 + lane];
    unsigned uB = xl[(size_t)sB * 64 + lane];

    int k = 0;
    for (; k + 1 < deg; k += 2) {
        int sC = (k + 2 < deg) ? ssrc[rs + k + 2] : 0;
        int sD = (k + 3 < deg) ? ssrc[rs + k + 3] : 0;
        unsigned uC = xl[(size_t)sC * 64 + lane];
        unsigned uD = xl[(size_t)sD * 64 + lane];
        float2 vA = bf2f(uA), vB = bf2f(uB);
        float tx = xd.x + vA.x, ty = xd.y + vA.y;
        tx = tx > 0.f ? tx : 0.2f * tx;
        ty = ty > 0.f ? ty : 0.2f * ty;
        float l0 = tx * attv.x + ty * attv.y;
        tx = xd.x + vB.x; ty = xd.y + vB.y;
        tx = tx > 0.f ? tx : 0.2f * tx;
        ty = ty > 0.f ? ty : 0.2f * ty;
        float l1 = tx * attv.x + ty * attv.y;
        #pragma unroll
        for (int o = 8; o; o >>= 1) {
            l0 += __shfl_xor(l0, o, 64);
            l1 += __shfl_xor(l1, o, 64);
        }
        float mn = fmaxf(fmaxf(m, l0), l1);
        float corr = __expf(m - mn);
        float w0 = __expf(l0 - mn);
        float w1 = __expf(l1 - mn);
        den  = den  * corr + w0 + w1;
        accx = accx * corr + w0 * vA.x + w1 * vB.x;
        accy = accy * corr + w0 * vA.y + w1 * vB.y;
        m = mn;
        sA = sC; sB = sD; uA = uC; uB = uD;
    }
    if (k < deg) {
        float2 vA = bf2f(uA);
        float tx = xd.x + vA.x, ty = xd.y + vA.y;
        tx = tx > 0.f ? tx : 0.2f * tx;
        ty = ty > 0.f ? ty : 0.2f * ty;
        float l0 = tx * attv.x + ty * attv.y;
        #pragma unroll
        for (int o = 8; o; o >>= 1) l0 += __shfl_xor(l0, o, 64);
        float mn = fmaxf(m, l0);
        float corr = __expf(m - mn);
        float w0 = __expf(l0 - mn);
        den  = den  * corr + w0;
        accx = accx * corr + w0 * vA.x;
        accy = accy * corr + w0 * vA.y;
    }

    float inv = (deg > 0) ? 1.f / den : 0.f;
    float2 o2;
    o2.x = accx * inv + bias[lane * 2];
    o2.y = accy * inv + bias[lane * 2 + 1];

    xrow[wid][lane * 2]     = o2.x;
    xrow[wid][lane * 2 + 1] = o2.y;
    float2 acc2 = *(const float2*)&bout[lane * 2];
    __syncthreads();
    #pragma unroll 4
    for (int kk = 0; kk < DD; ++kk) {
        float xv = xrow[wid][kk];
        float2 wv2 = *(const float2*)&wout[(size_t)kk * DD + lane * 2];
        acc2.x += xv * wv2.x;
        acc2.y += xv * wv2.y;
    }
    float s = acc2.x + acc2.y;
    #pragma unroll
    for (int o = 32; o; o >>= 1) s += __shfl_xor(s, o, 64);
    float mean = s * (1.f / 128.f);
    float dx = acc2.x - mean, dy = acc2.y - mean;
    float s2 = dx * dx + dy * dy;
    #pragma unroll
    for (int o = 32; o; o >>= 1) s2 += __shfl_xor(s2, o, 64);
    float rstd = rsqrtf(s2 * (1.f / 128.f) + 1e-12f);
    float2 g2 = *(const float2*)&gamma[lane * 2];
    float2 b2 = *(const float2*)&beta[lane * 2];
    float2 yo;
    yo.x = dx * rstd * g2.x + b2.x;
    yo.y = dy * rstd * g2.y + b2.y;
    *(float2*)&yout[(size_t)node * DD + lane * 2] = yo;
}

extern "C" void kernel_launch(void* const* d_in, const int* in_sizes, int n_in,
                              void* d_out, int out_size, void* d_ws, size_t ws_size,
                              hipStream_t stream) {
    const float* embs  = (const float*)d_in[0];
    const float* w0    = (const float*)d_in[1];
    const float* b0    = (const float*)d_in[2];
    const float* att0  = (const float*)d_in[3];
    const float* bias0 = (const float*)d_in[4];
    const float* w1    = (const float*)d_in[5];
    const float* b1    = (const float*)d_in[6];
    const float* att1  = (const float*)d_in[7];
    const float* bias1 = (const float*)d_in[8];
    const float* wout  = (const float*)d_in[9];
    const float* bout  = (const float*)d_in[10];
    const float* gamma = (const float*)d_in[11];
    const float* beta  = (const float*)d_in[12];
    const int* ei0 = (const int*)d_in[13];
    const int* ei1 = (const int*)d_in[14];

    int N  = in_sizes[0] / DD;
    int E0 = in_sizes[13] / 2;
    int E1 = in_sizes[14] / 2;
    int BS = out_size / DD;
    int n2 = N + BS;
    int W  = (N + 31) / 32;

    // ---- workspace carve-up ----
    unsigned* xl   = (unsigned*)d_ws;                      // N*64 (bf16 pairs)
    float* out     = (float*)(xl + (size_t)N * 64);        // N*128 f32
    int* ssrc      = (int*)(out + (size_t)N * DD);         // n2*SLOT
    int* cnt       = ssrc + (size_t)n2 * SLOT;             // n2   (memset)
    unsigned* mb   = (unsigned*)(cnt + n2);                // W+32 (memset, adjacent)
    int* mex       = (int*)(mb + W + 32);                  // W
    int* mbsum     = mex + W;                              // 32
    int* livelist  = mbsum + 32;                           // N
    int* nLive     = livelist + N;                         // 1

    int gH0  = (E0 + 1023) / 1024;
    int gH1  = (E1 + 1023) / 1024;
    int gLin = (N + 63) / 64;
    int gMs  = (W + 255) / 256;

    // 1. zero cnt + maskbits (contiguous)
    hipMemsetAsync(cnt, 0, ((size_t)n2 + W + 32) * sizeof(int), stream);
    // 2. mark live nodes (bitmask)
    k_mark<<<gH1, 256, 0, stream>>>(ei1, ei1 + E1, E1, BS, mb);
    // 3. F1: linear0 || hist+fill conv0 || hist+fill conv1 || mscanA
    k_hflin<<<gLin + gH0 + gH1 + gMs, 256, 0, stream>>>(
        embs, w0, b0, xl, N, gLin, gH0, gH1,
        ei0, ei0 + E0, E0, ei1, ei1 + E1, E1, BS,
        mb, cnt, ssrc, N, W, mex, mbsum);
    // 4. agg0 (mask-gated) with livelist-build in leading blocks
    k_aggL<<<gMs + (N + 3) / 4, 256, 0, stream>>>(
        xl, cnt, ssrc, att0, bias0, out, mb, N, gMs, W,
        mex, mbsum, livelist, nLive);
    // 5. lin1 over live rows only (gelu)
    k_linC<<<gLin, 256, 0, stream>>>(out, w1, b1, xl, livelist, nLive);
    // 6. agg1 (dst<BS) + head
    k_agg1head<<<(BS + 3) / 4, 256, 0, stream>>>(
        xl, cnt, ssrc, att1, bias1,
        wout, bout, gamma, beta, (float*)d_out, N, BS);
}

// Round 12
// 112.347 us; speedup vs baseline: 1.2453x; 1.2453x over previous
//
#include <hip/hip_runtime.h>
#include <math.h>

#define DD 128
#define SLOT 64   // fixed CSR bucket stride; deg~Poisson(12.8), P(>64) ~ 0

__device__ __forceinline__ unsigned bf16rne(float f) {
    unsigned u = __float_as_uint(f);
    return (u + 0x7FFFu + ((u >> 16) & 1u)) >> 16;
}
__device__ __forceinline__ float2 bf2f(unsigned u) {
    float2 r;
    r.x = __uint_as_float(u << 16);
    r.y = __uint_as_float(u & 0xFFFF0000u);
    return r;
}

// ---- mark live nodes into a BITMASK (6.25 KB -> L1-resident) ---------------
__global__ __launch_bounds__(256) void k_mark(const int* __restrict__ src1,
                                              const int* __restrict__ dst1,
                                              int E1, int BS,
                                              unsigned* __restrict__ mb) {
    int base = blockIdx.x * 1024 + threadIdx.x;
    #pragma unroll
    for (int j = 0; j < 4; ++j) {
        int e = base + j * 256;
        if (e < E1) {
            int d = dst1[e];
            if (d < BS) {
                int s = src1[e];
                atomicOr(&mb[s >> 5], 1u << (s & 31));
            }
        }
    }
    int g = blockIdx.x * 256 + threadIdx.x;
    if (g < BS) atomicOr(&mb[g >> 5], 1u << (g & 31));
}

// ---- F1: linear0 (32-row tiles, R9-proven) || hist+fill both || mscanA -----
__global__ __launch_bounds__(256) void k_hflin(
        const float* __restrict__ x, const float* __restrict__ w,
        const float* __restrict__ b, unsigned* __restrict__ y, int nrows,
        int gLin, int gH0, int gH1,
        const int* __restrict__ src0, const int* __restrict__ dst0, int E0,
        const int* __restrict__ src1, const int* __restrict__ dst1, int E1,
        int BS, const unsigned* __restrict__ mb, int* __restrict__ cnt,
        int* __restrict__ ssrc, int N,
        int W, int* __restrict__ mex, int* __restrict__ mbsum) {
    __shared__ float  xs[32][DD];     // 16 KB
    __shared__ float4 wb[32][32];     // 16 KB

    if (blockIdx.x >= gLin) {
        int role = blockIdx.x - gLin;
        if (role < gH0) {                       // hist+fill conv0 (live dst)
            int base = role * 1024 + threadIdx.x;
            #pragma unroll
            for (int j = 0; j < 4; ++j) {
                int e = base + j * 256;
                if (e < E0) {
                    int d = dst0[e];
                    if ((mb[d >> 5] >> (d & 31)) & 1u) {
                        int r = atomicAdd(&cnt[d], 1);
                        if (r < SLOT) ssrc[(size_t)d * SLOT + r] = src0[e];
                    }
                }
            }
        } else if (role < gH0 + gH1) {          // hist+fill conv1 (dst < BS)
            int base = (role - gH0) * 1024 + threadIdx.x;
            #pragma unroll
            for (int j = 0; j < 4; ++j) {
                int e = base + j * 256;
                if (e < E1) {
                    int d = dst1[e];
                    if (d < BS) {
                        int r = atomicAdd(&cnt[N + d], 1);
                        if (r < SLOT) ssrc[(size_t)(N + d) * SLOT + r] = src1[e];
                    }
                }
            }
        } else {                                // mscanA over mask words
            __shared__ int s[256];
            int idx = (role - gH0 - gH1) * 256 + threadIdx.x;
            int v = (idx < W) ? __popc(mb[idx]) : 0;
            s[threadIdx.x] = v;
            __syncthreads();
            for (int o = 1; o < 256; o <<= 1) {
                int t = (threadIdx.x >= o) ? s[threadIdx.x - o] : 0;
                __syncthreads();
                s[threadIdx.x] += t;
                __syncthreads();
            }
            if (idx < W) mex[idx] = s[threadIdx.x] - v;
            if (threadIdx.x == 255) mbsum[role - gH0 - gH1] = s[255];
        }
        return;
    }

    // ---- linear: 32 rows x 128 cols (R9-proven structure) ----
    int rbase = blockIdx.x * 32;
    for (int i = threadIdx.x; i < 32 * 32; i += 256) {
        int r = rbase + (i >> 5);
        float4 v = make_float4(0.f, 0.f, 0.f, 0.f);
        if (r < nrows) v = ((const float4*)x)[(size_t)r * 32 + (i & 31)];
        *(float4*)&xs[i >> 5][(i & 31) * 4] = v;
    }
    int g  = threadIdx.x >> 5;
    int cg = threadIdx.x & 31;
    float4 bb = ((const float4*)b)[cg];
    float4 acc[4];
    #pragma unroll
    for (int r = 0; r < 4; ++r) acc[r] = bb;
    const float4* wv = (const float4*)w;
    for (int kc = 0; kc < DD; kc += 32) {
        __syncthreads();
        for (int i = threadIdx.x; i < 32 * 32; i += 256)
            wb[i >> 5][i & 31] = wv[(size_t)(kc + (i >> 5)) * 32 + (i & 31)];
        __syncthreads();
        #pragma unroll 8
        for (int kk = 0; kk < 32; ++kk) {
            float4 wk = wb[kk][cg];
            #pragma unroll
            for (int r = 0; r < 4; ++r) {
                float xv = xs[g * 4 + r][kc + kk];
                acc[r].x += xv * wk.x; acc[r].y += xv * wk.y;
                acc[r].z += xv * wk.z; acc[r].w += xv * wk.w;
            }
        }
    }
    #pragma unroll
    for (int r = 0; r < 4; ++r) {
        int row = rbase + g * 4 + r;
        if (row < nrows) {
            uint2 p;
            p.x = bf16rne(acc[r].x) | (bf16rne(acc[r].y) << 16);
            p.y = bf16rne(acc[r].z) | (bf16rne(acc[r].w) << 16);
            ((uint2*)y)[(size_t)row * 32 + cg] = p;
        }
    }
}

// ---- agg0 (mask-gated, all nodes) with leading livelist-build blocks -------
__global__ __launch_bounds__(256) void k_aggL(const unsigned* __restrict__ xl,
                                              const int* __restrict__ cnt,
                                              const int* __restrict__ ssrc,
                                              const float* __restrict__ att,
                                              const float* __restrict__ bias,
                                              float* __restrict__ out,
                                              const unsigned* __restrict__ mb,
                                              int n, int gMs, int W,
                                              const int* __restrict__ mex,
                                              const int* __restrict__ mbsum,
                                              int* __restrict__ livelist,
                                              int* __restrict__ nLive) {
    if (blockIdx.x < gMs) {
        int pre = 0;
        for (int i = 0; i < (int)blockIdx.x; ++i) pre += mbsum[i];
        int idx = blockIdx.x * 256 + threadIdx.x;
        if (idx < W) {
            unsigned word = mb[idx];
            int base = mex[idx] + pre;
            unsigned wt = word;
            while (wt) {
                int bit = __ffs(wt) - 1;
                livelist[base + __popc(word & ((1u << bit) - 1u))] = idx * 32 + bit;
                wt &= wt - 1;
            }
            if (idx == W - 1) *nLive = base + __popc(word);
        }
        return;
    }
    int node = __builtin_amdgcn_readfirstlane((blockIdx.x - gMs) * 4 +
                                              (threadIdx.x >> 6));
    if (node >= n) return;
    if (!((mb[node >> 5] >> (node & 31)) & 1u)) return;
    int lane = threadIdx.x & 63;
    float2 attv = *(const float2*)&att[lane * 2];
    float2 xd = bf2f(xl[(size_t)node * 64 + lane]);
    int rs  = node * SLOT;
    int deg = cnt[node];
    deg = deg > SLOT ? SLOT : deg;

    float m = -3.4e38f, den = 0.f, accx = 0.f, accy = 0.f;
    int sA = (deg > 0) ? ssrc[rs] : 0;
    int sB = (deg > 1) ? ssrc[rs + 1] : 0;
    unsigned uA = xl[(size_t)sA * 64 + lane];
    unsigned uB = xl[(size_t)sB * 64 + lane];

    int k = 0;
    for (; k + 1 < deg; k += 2) {
        int sC = (k + 2 < deg) ? ssrc[rs + k + 2] : 0;
        int sD = (k + 3 < deg) ? ssrc[rs + k + 3] : 0;
        unsigned uC = xl[(size_t)sC * 64 + lane];
        unsigned uD = xl[(size_t)sD * 64 + lane];
        float2 vA = bf2f(uA), vB = bf2f(uB);

        float tx = xd.x + vA.x, ty = xd.y + vA.y;
        tx = tx > 0.f ? tx : 0.2f * tx;
        ty = ty > 0.f ? ty : 0.2f * ty;
        float l0 = tx * attv.x + ty * attv.y;
        tx = xd.x + vB.x; ty = xd.y + vB.y;
        tx = tx > 0.f ? tx : 0.2f * tx;
        ty = ty > 0.f ? ty : 0.2f * ty;
        float l1 = tx * attv.x + ty * attv.y;
        #pragma unroll
        for (int o = 8; o; o >>= 1) {
            l0 += __shfl_xor(l0, o, 64);
            l1 += __shfl_xor(l1, o, 64);
        }
        float mn = fmaxf(fmaxf(m, l0), l1);
        float corr = __expf(m - mn);
        float w0 = __expf(l0 - mn);
        float w1 = __expf(l1 - mn);
        den  = den  * corr + w0 + w1;
        accx = accx * corr + w0 * vA.x + w1 * vB.x;
        accy = accy * corr + w0 * vA.y + w1 * vB.y;
        m = mn;
        sA = sC; sB = sD; uA = uC; uB = uD;
    }
    if (k < deg) {
        float2 vA = bf2f(uA);
        float tx = xd.x + vA.x, ty = xd.y + vA.y;
        tx = tx > 0.f ? tx : 0.2f * tx;
        ty = ty > 0.f ? ty : 0.2f * ty;
        float l0 = tx * attv.x + ty * attv.y;
        #pragma unroll
        for (int o = 8; o; o >>= 1) l0 += __shfl_xor(l0, o, 64);
        float mn = fmaxf(m, l0);
        float corr = __expf(m - mn);
        float w0 = __expf(l0 - mn);
        den  = den  * corr + w0;
        accx = accx * corr + w0 * vA.x;
        accy = accy * corr + w0 * vA.y;
    }

    float inv = (deg > 0) ? 1.f / den : 0.f;
    float2 o2;
    o2.x = accx * inv + bias[lane * 2];
    o2.y = accy * inv + bias[lane * 2 + 1];
    *(float2*)&out[(size_t)node * DD + lane * 2] = o2;
}

// ---- lin1 over livelist rows (gelu on input, 32-row tiles, R9 structure) ---
__global__ __launch_bounds__(256) void k_linC(const float* __restrict__ x,
                                              const float* __restrict__ w,
                                              const float* __restrict__ b,
                                              unsigned* __restrict__ y,
                                              const int* __restrict__ livelist,
                                              const int* __restrict__ nLive) {
    __shared__ float  xs[32][DD];
    __shared__ float4 wb[32][32];
    int nL = *nLive;
    int lbase = blockIdx.x * 32;
    if (lbase >= nL) return;

    for (int i = threadIdx.x; i < 32 * 32; i += 256) {
        int li = lbase + (i >> 5);
        float4 v = make_float4(0.f, 0.f, 0.f, 0.f);
        if (li < nL) {
            int r = livelist[li];
            v = ((const float4*)x)[(size_t)r * 32 + (i & 31)];
            v.x = 0.5f * v.x * (1.f + erff(v.x * 0.70710678f));
            v.y = 0.5f * v.y * (1.f + erff(v.y * 0.70710678f));
            v.z = 0.5f * v.z * (1.f + erff(v.z * 0.70710678f));
            v.w = 0.5f * v.w * (1.f + erff(v.w * 0.70710678f));
        }
        *(float4*)&xs[i >> 5][(i & 31) * 4] = v;
    }
    int g  = threadIdx.x >> 5;
    int cg = threadIdx.x & 31;
    float4 bb = ((const float4*)b)[cg];
    float4 acc[4];
    #pragma unroll
    for (int r = 0; r < 4; ++r) acc[r] = bb;
    const float4* wv = (const float4*)w;
    for (int kc = 0; kc < DD; kc += 32) {
        __syncthreads();
        for (int i = threadIdx.x; i < 32 * 32; i += 256)
            wb[i >> 5][i & 31] = wv[(size_t)(kc + (i >> 5)) * 32 + (i & 31)];
        __syncthreads();
        #pragma unroll 8
        for (int kk = 0; kk < 32; ++kk) {
            float4 wk = wb[kk][cg];
            #pragma unroll
            for (int r = 0; r < 4; ++r) {
                float xv = xs[g * 4 + r][kc + kk];
                acc[r].x += xv * wk.x; acc[r].y += xv * wk.y;
                acc[r].z += xv * wk.z; acc[r].w += xv * wk.w;
            }
        }
    }
    #pragma unroll
    for (int r = 0; r < 4; ++r) {
        int li = lbase + g * 4 + r;
        if (li < nL) {
            int row = livelist[li];
            uint2 p;
            p.x = bf16rne(acc[r].x) | (bf16rne(acc[r].y) << 16);
            p.y = bf16rne(acc[r].z) | (bf16rne(acc[r].w) << 16);
            ((uint2*)y)[(size_t)row * 32 + cg] = p;
        }
    }
}

// ---- agg1 (nodes [0,BS)) fused with linear+LayerNorm head -------------------
__global__ __launch_bounds__(256) void k_agg1head(
        const unsigned* __restrict__ xl,
        const int* __restrict__ cnt, const int* __restrict__ ssrc,
        const float* __restrict__ att, const float* __restrict__ bias,
        const float* __restrict__ wout, const float* __restrict__ bout,
        const float* __restrict__ gamma, const float* __restrict__ beta,
        float* __restrict__ yout, int N, int BS) {
    __shared__ float xrow[4][DD];
    int wid  = threadIdx.x >> 6;
    int lane = threadIdx.x & 63;
    int node = blockIdx.x * 4 + wid;
    if (node >= BS) return;
    float2 attv = *(const float2*)&att[lane * 2];
    float2 xd = bf2f(xl[(size_t)node * 64 + lane]);
    int key = N + node;
    int rs  = key * SLOT;
    int deg = cnt[key];
    deg = deg > SLOT ? SLOT : deg;

    float m = -3.4e38f, den = 0.f, accx = 0.f, accy = 0.f;
    int sA = (deg > 0) ? ssrc[rs] : 0;
    int sB = (deg > 1) ? ssrc[rs + 1] : 0;
    unsigned uA = xl[(size_t)sA * 64 + lane];
    unsigned uB = xl[(size_t)sB * 64 + lane];

    int k = 0;
    for (; k + 1 < deg; k += 2) {
        int sC = (k + 2 < deg) ? ssrc[rs + k + 2] : 0;
        int sD = (k + 3 < deg) ? ssrc[rs + k + 3] : 0;
        unsigned uC = xl[(size_t)sC * 64 + lane];
        unsigned uD = xl[(size_t)sD * 64 + lane];
        float2 vA = bf2f(uA), vB = bf2f(uB);
        float tx = xd.x + vA.x, ty = xd.y + vA.y;
        tx = tx > 0.f ? tx : 0.2f * tx;
        ty = ty > 0.f ? ty : 0.2f * ty;
        float l0 = tx * attv.x + ty * attv.y;
        tx = xd.x + vB.x; ty = xd.y + vB.y;
        tx = tx > 0.f ? tx : 0.2f * tx;
        ty = ty > 0.f ? ty : 0.2f * ty;
        float l1 = tx * attv.x + ty * attv.y;
        #pragma unroll
        for (int o = 8; o; o >>= 1) {
            l0 += __shfl_xor(l0, o, 64);
            l1 += __shfl_xor(l1, o, 64);
        }
        float mn = fmaxf(fmaxf(m, l0), l1);
        float corr = __expf(m - mn);
        float w0 = __expf(l0 - mn);
        float w1 = __expf(l1 - mn);
        den  = den  * corr + w0 + w1;
        accx = accx * corr + w0 * vA.x + w1 * vB.x;
        accy = accy * corr + w0 * vA.y + w1 * vB.y;
        m = mn;
        sA = sC; sB = sD; uA = uC; uB = uD;
    }
    if (k < deg) {
        float2 vA = bf2f(uA);
        float tx = xd.x + vA.x, ty = xd.y + vA.y;
        tx = tx > 0.f ? tx : 0.2f * tx;
        ty = ty > 0.f ? ty : 0.2f * ty;
        float l0 = tx * attv.x + ty * attv.y;
        #pragma unroll
        for (int o = 8; o; o >>= 1) l0 += __shfl_xor(l0, o, 64);
        float mn = fmaxf(m, l0);
        float corr = __expf(m - mn);
        float w0 = __expf(l0 - mn);
        den  = den  * corr + w0;
        accx = accx * corr + w0 * vA.x;
        accy = accy * corr + w0 * vA.y;
    }

    float inv = (deg > 0) ? 1.f / den : 0.f;
    float2 o2;
    o2.x = accx * inv + bias[lane * 2];
    o2.y = accy * inv + bias[lane * 2 + 1];

    xrow[wid][lane * 2]     = o2.x;
    xrow[wid][lane * 2 + 1] = o2.y;
    float2 acc2 = *(const float2*)&bout[lane * 2];
    __syncthreads();
    #pragma unroll 4
    for (int kk = 0; kk < DD; ++kk) {
        float xv = xrow[wid][kk];
        float2 wv2 = *(const float2*)&wout[(size_t)kk * DD + lane * 2];
        acc2.x += xv * wv2.x;
        acc2.y += xv * wv2.y;
    }
    float s = acc2.x + acc2.y;
    #pragma unroll
    for (int o = 32; o; o >>= 1) s += __shfl_xor(s, o, 64);
    float mean = s * (1.f / 128.f);
    float dx = acc2.x - mean, dy = acc2.y - mean;
    float s2 = dx * dx + dy * dy;
    #pragma unroll
    for (int o = 32; o; o >>= 1) s2 += __shfl_xor(s2, o, 64);
    float rstd = rsqrtf(s2 * (1.f / 128.f) + 1e-12f);
    float2 g2 = *(const float2*)&gamma[lane * 2];
    float2 b2 = *(const float2*)&beta[lane * 2];
    float2 yo;
    yo.x = dx * rstd * g2.x + b2.x;
    yo.y = dy * rstd * g2.y + b2.y;
    *(float2*)&yout[(size_t)node * DD + lane * 2] = yo;
}

extern "C" void kernel_launch(void* const* d_in, const int* in_sizes, int n_in,
                              void* d_out, int out_size, void* d_ws, size_t ws_size,
                              hipStream_t stream) {
    const float* embs  = (const float*)d_in[0];
    const float* w0    = (const float*)d_in[1];
    const float* b0    = (const float*)d_in[2];
    const float* att0  = (const float*)d_in[3];
    const float* bias0 = (const float*)d_in[4];
    const float* w1    = (const float*)d_in[5];
    const float* b1    = (const float*)d_in[6];
    const float* att1  = (const float*)d_in[7];
    const float* bias1 = (const float*)d_in[8];
    const float* wout  = (const float*)d_in[9];
    const float* bout  = (const float*)d_in[10];
    const float* gamma = (const float*)d_in[11];
    const float* beta  = (const float*)d_in[12];
    const int* ei0 = (const int*)d_in[13];
    const int* ei1 = (const int*)d_in[14];

    int N  = in_sizes[0] / DD;
    int E0 = in_sizes[13] / 2;
    int E1 = in_sizes[14] / 2;
    int BS = out_size / DD;
    int n2 = N + BS;
    int W  = (N + 31) / 32;

    // ---- workspace carve-up ----
    unsigned* xl   = (unsigned*)d_ws;                      // N*64 (bf16 pairs)
    float* out     = (float*)(xl + (size_t)N * 64);        // N*128 f32
    int* ssrc      = (int*)(out + (size_t)N * DD);         // n2*SLOT
    int* cnt       = ssrc + (size_t)n2 * SLOT;             // n2   (memset)
    unsigned* mb   = (unsigned*)(cnt + n2);                // W+32 (memset, adjacent)
    int* mex       = (int*)(mb + W + 32);                  // W
    int* mbsum     = mex + W;                              // 32
    int* livelist  = mbsum + 32;                           // N
    int* nLive     = livelist + N;                         // 1

    int gH0  = (E0 + 1023) / 1024;
    int gH1  = (E1 + 1023) / 1024;
    int gLin = (N + 31) / 32;
    int gMs  = (W + 255) / 256;

    // 1. zero cnt + maskbits (contiguous)
    hipMemsetAsync(cnt, 0, ((size_t)n2 + W + 32) * sizeof(int), stream);
    // 2. mark live nodes (bitmask)
    k_mark<<<gH1, 256, 0, stream>>>(ei1, ei1 + E1, E1, BS, mb);
    // 3. F1: linear0 || hist+fill conv0 || hist+fill conv1 || mscanA
    k_hflin<<<gLin + gH0 + gH1 + gMs, 256, 0, stream>>>(
        embs, w0, b0, xl, N, gLin, gH0, gH1,
        ei0, ei0 + E0, E0, ei1, ei1 + E1, E1, BS,
        mb, cnt, ssrc, N, W, mex, mbsum);
    // 4. agg0 (mask-gated) with livelist-build in leading blocks
    k_aggL<<<gMs + (N + 3) / 4, 256, 0, stream>>>(
        xl, cnt, ssrc, att0, bias0, out, mb, N, gMs, W,
        mex, mbsum, livelist, nLive);
    // 5. lin1 over live rows only (gelu)
    k_linC<<<gLin, 256, 0, stream>>>(out, w1, b1, xl, livelist, nLive);
    // 6. agg1 (dst<BS) + head
    k_agg1head<<<(BS + 3) / 4, 256, 0, stream>>>(
        xl, cnt, ssrc, att1, bias1,
        wout, bout, gamma, beta, (float*)d_out, N, BS);
}

// Round 13
// 94.580 us; speedup vs baseline: 1.4792x; 1.1878x over previous
//
#include <hip/hip_runtime.h>
#include <math.h>

#define DD 128
#define SLOT 64   // fixed CSR bucket stride; deg~Poisson(12.8), P(>64) ~ 0

typedef short bf16x8 __attribute__((ext_vector_type(8)));
typedef float f32x4  __attribute__((ext_vector_type(4)));

__device__ __forceinline__ unsigned bf16rne(float f) {
    unsigned u = __float_as_uint(f);
    return (u + 0x7FFFu + ((u >> 16) & 1u)) >> 16;
}
__device__ __forceinline__ float2 bf2f(unsigned u) {
    float2 r;
    r.x = __uint_as_float(u << 16);
    r.y = __uint_as_float(u & 0xFFFF0000u);
    return r;
}
__device__ __forceinline__ float gelu1(float v) {
    return 0.5f * v * (1.f + erff(v * 0.70710678118654752f));
}

// ---- mark live nodes (bitmask) + pack w0/w1 into B-fragment layout ---------
// B-frag layout for mfma_f32_16x16x32_bf16: lane=(c&15)|(((k>>3)&3)<<4),
// elem j=k&7, tile (nt=c>>4, ks=k>>5). Same k-mapping used for A fragments.
__global__ __launch_bounds__(256) void k_mark(const int* __restrict__ src1,
                                              const int* __restrict__ dst1,
                                              int E1, int BS,
                                              unsigned* __restrict__ mb,
                                              const float* __restrict__ w0,
                                              const float* __restrict__ w1,
                                              unsigned short* __restrict__ wp0,
                                              unsigned short* __restrict__ wp1) {
    int idx = blockIdx.x * 256 + threadIdx.x;
    if (idx < 2 * DD * DD) {
        const float* w = (idx < DD * DD) ? w0 : w1;
        unsigned short* wp = (idx < DD * DD) ? wp0 : wp1;
        int i = idx & (DD * DD - 1);
        int k = i >> 7, c = i & 127;
        int nt = c >> 4, ks = k >> 5;
        int lane = (c & 15) | (((k >> 3) & 3) << 4);
        wp[(((nt * 4 + ks) * 64) + lane) * 8 + (k & 7)] =
            (unsigned short)bf16rne(w[k * DD + c]);
    }
    int base = blockIdx.x * 1024 + threadIdx.x;
    #pragma unroll
    for (int j = 0; j < 4; ++j) {
        int e = base + j * 256;
        if (e < E1) {
            int d = dst1[e];
            if (d < BS) {
                int s = src1[e];
                atomicOr(&mb[s >> 5], 1u << (s & 31));
            }
        }
    }
    int g = blockIdx.x * 256 + threadIdx.x;
    if (g < BS) atomicOr(&mb[g >> 5], 1u << (g & 31));
}

// ---- MFMA linear tile: 64 rows/block (4 waves x 16 rows), y = bf16(x@w + b)
// Returns via xl (uint col-pairs). No LDS, no barriers.
__device__ __forceinline__ void mfma_linear_rows(
        const float* __restrict__ x, const unsigned short* __restrict__ wp,
        const float* __restrict__ b, unsigned* __restrict__ xl,
        int rIn, int rowValid, int rbaseOut, int nrowsOut, int apply_gelu) {
    int lane = threadIdx.x & 63;
    int c = lane & 15, g = lane >> 4;
    f32x4 acc[8];
    #pragma unroll
    for (int nt = 0; nt < 8; ++nt) {
        float bb = b[nt * 16 + c];
        acc[nt] = (f32x4){bb, bb, bb, bb};
    }
    const bf16x8* wv = (const bf16x8*)wp;
    for (int ks = 0; ks < 4; ++ks) {
        float xr[8];
        if (rowValid) {
            const float4* xp = (const float4*)&x[(size_t)rIn * DD + ks * 32 + g * 8];
            *(float4*)&xr[0] = xp[0];
            *(float4*)&xr[4] = xp[1];
            if (apply_gelu) {
                #pragma unroll
                for (int j = 0; j < 8; ++j) xr[j] = gelu1(xr[j]);
            }
        } else {
            #pragma unroll
            for (int j = 0; j < 8; ++j) xr[j] = 0.f;
        }
        union { unsigned u[4]; bf16x8 v; } af;
        #pragma unroll
        for (int j = 0; j < 4; ++j)
            af.u[j] = bf16rne(xr[2 * j]) | (bf16rne(xr[2 * j + 1]) << 16);
        #pragma unroll
        for (int nt = 0; nt < 8; ++nt) {
            bf16x8 bv = wv[(nt * 4 + ks) * 64 + lane];
            acc[nt] = __builtin_amdgcn_mfma_f32_16x16x32_bf16(af.v, bv, acc[nt], 0, 0, 0);
        }
    }
    // epilogue: D col = lane&15 (tile nt), row = 4*(lane>>4)+reg
    int g4 = g * 4;
    #pragma unroll
    for (int nt = 0; nt < 8; ++nt) {
        #pragma unroll
        for (int reg = 0; reg < 4; ++reg) {
            unsigned u = bf16rne(acc[nt][reg]);
            unsigned up = (unsigned)__shfl_xor((int)u, 1, 64);
            int row = rbaseOut + g4 + reg;
            if (!(c & 1) && row < nrowsOut)
                xl[(size_t)row * 64 + (nt * 16 + c) / 2] = u | (up << 16);
        }
    }
}

// ---- F1: MFMA linear0 || hist+fill both convs || mscanA --------------------
__global__ __launch_bounds__(256) void k_hflin(
        const float* __restrict__ x, const unsigned short* __restrict__ wp,
        const float* __restrict__ b, unsigned* __restrict__ y, int nrows,
        int gLin, int gH0, int gH1,
        const int* __restrict__ src0, const int* __restrict__ dst0, int E0,
        const int* __restrict__ src1, const int* __restrict__ dst1, int E1,
        int BS, const unsigned* __restrict__ mb, int* __restrict__ cnt,
        int* __restrict__ ssrc, int N,
        int W, int* __restrict__ mex, int* __restrict__ mbsum) {
    if (blockIdx.x >= gLin) {
        int role = blockIdx.x - gLin;
        if (role < gH0) {                       // hist+fill conv0 (live dst)
            int base = role * 1024 + threadIdx.x;
            #pragma unroll
            for (int j = 0; j < 4; ++j) {
                int e = base + j * 256;
                if (e < E0) {
                    int d = dst0[e];
                    if ((mb[d >> 5] >> (d & 31)) & 1u) {
                        int r = atomicAdd(&cnt[d], 1);
                        if (r < SLOT) ssrc[(size_t)d * SLOT + r] = src0[e];
                    }
                }
            }
        } else if (role < gH0 + gH1) {          // hist+fill conv1 (dst < BS)
            int base = (role - gH0) * 1024 + threadIdx.x;
            #pragma unroll
            for (int j = 0; j < 4; ++j) {
                int e = base + j * 256;
                if (e < E1) {
                    int d = dst1[e];
                    if (d < BS) {
                        int r = atomicAdd(&cnt[N + d], 1);
                        if (r < SLOT) ssrc[(size_t)(N + d) * SLOT + r] = src1[e];
                    }
                }
            }
        } else {                                // mscanA over mask words
            __shared__ int s[256];
            int idx = (role - gH0 - gH1) * 256 + threadIdx.x;
            int v = (idx < W) ? __popc(mb[idx]) : 0;
            s[threadIdx.x] = v;
            __syncthreads();
            for (int o = 1; o < 256; o <<= 1) {
                int t = (threadIdx.x >= o) ? s[threadIdx.x - o] : 0;
                __syncthreads();
                s[threadIdx.x] += t;
                __syncthreads();
            }
            if (idx < W) mex[idx] = s[threadIdx.x] - v;
            if (threadIdx.x == 255) mbsum[role - gH0 - gH1] = s[255];
        }
        return;
    }
    int wave = threadIdx.x >> 6;
    int rb = blockIdx.x * 64 + wave * 16;
    int rIn = rb + ((threadIdx.x & 63) & 15);
    mfma_linear_rows(x, wp, b, y, rIn, rIn < nrows, rb, nrows, 0);
}

// ---- agg0 (mask-gated, all nodes) with leading livelist-build blocks -------
__global__ __launch_bounds__(256) void k_aggL(const unsigned* __restrict__ xl,
                                              const int* __restrict__ cnt,
                                              const int* __restrict__ ssrc,
                                              const float* __restrict__ att,
                                              const float* __restrict__ bias,
                                              float* __restrict__ out,
                                              const unsigned* __restrict__ mb,
                                              int n, int gMs, int W,
                                              const int* __restrict__ mex,
                                              const int* __restrict__ mbsum,
                                              int* __restrict__ livelist,
                                              int* __restrict__ nLive) {
    if (blockIdx.x < gMs) {
        int pre = 0;
        for (int i = 0; i < (int)blockIdx.x; ++i) pre += mbsum[i];
        int idx = blockIdx.x * 256 + threadIdx.x;
        if (idx < W) {
            unsigned word = mb[idx];
            int base = mex[idx] + pre;
            unsigned wt = word;
            while (wt) {
                int bit = __ffs(wt) - 1;
                livelist[base + __popc(word & ((1u << bit) - 1u))] = idx * 32 + bit;
                wt &= wt - 1;
            }
            if (idx == W - 1) *nLive = base + __popc(word);
        }
        return;
    }
    int node = __builtin_amdgcn_readfirstlane((blockIdx.x - gMs) * 4 +
                                              (threadIdx.x >> 6));
    if (node >= n) return;
    if (!((mb[node >> 5] >> (node & 31)) & 1u)) return;
    int lane = threadIdx.x & 63;
    float2 attv = *(const float2*)&att[lane * 2];
    float2 xd = bf2f(xl[(size_t)node * 64 + lane]);
    int rs  = node * SLOT;
    int deg = cnt[node];
    deg = deg > SLOT ? SLOT : deg;

    float m = -3.4e38f, den = 0.f, accx = 0.f, accy = 0.f;
    int sA = (deg > 0) ? ssrc[rs] : 0;
    int sB = (deg > 1) ? ssrc[rs + 1] : 0;
    unsigned uA = xl[(size_t)sA * 64 + lane];
    unsigned uB = xl[(size_t)sB * 64 + lane];

    int k = 0;
    for (; k + 1 < deg; k += 2) {
        int sC = (k + 2 < deg) ? ssrc[rs + k + 2] : 0;
        int sD = (k + 3 < deg) ? ssrc[rs + k + 3] : 0;
        unsigned uC = xl[(size_t)sC * 64 + lane];
        unsigned uD = xl[(size_t)sD * 64 + lane];
        float2 vA = bf2f(uA), vB = bf2f(uB);

        float tx = xd.x + vA.x, ty = xd.y + vA.y;
        tx = tx > 0.f ? tx : 0.2f * tx;
        ty = ty > 0.f ? ty : 0.2f * ty;
        float l0 = tx * attv.x + ty * attv.y;
        tx = xd.x + vB.x; ty = xd.y + vB.y;
        tx = tx > 0.f ? tx : 0.2f * tx;
        ty = ty > 0.f ? ty : 0.2f * ty;
        float l1 = tx * attv.x + ty * attv.y;
        #pragma unroll
        for (int o = 8; o; o >>= 1) {
            l0 += __shfl_xor(l0, o, 64);
            l1 += __shfl_xor(l1, o, 64);
        }
        float mn = fmaxf(fmaxf(m, l0), l1);
        float corr = __expf(m - mn);
        float w0 = __expf(l0 - mn);
        float w1 = __expf(l1 - mn);
        den  = den  * corr + w0 + w1;
        accx = accx * corr + w0 * vA.x + w1 * vB.x;
        accy = accy * corr + w0 * vA.y + w1 * vB.y;
        m = mn;
        sA = sC; sB = sD; uA = uC; uB = uD;
    }
    if (k < deg) {
        float2 vA = bf2f(uA);
        float tx = xd.x + vA.x, ty = xd.y + vA.y;
        tx = tx > 0.f ? tx : 0.2f * tx;
        ty = ty > 0.f ? ty : 0.2f * ty;
        float l0 = tx * attv.x + ty * attv.y;
        #pragma unroll
        for (int o = 8; o; o >>= 1) l0 += __shfl_xor(l0, o, 64);
        float mn = fmaxf(m, l0);
        float corr = __expf(m - mn);
        float w0 = __expf(l0 - mn);
        den  = den  * corr + w0;
        accx = accx * corr + w0 * vA.x;
        accy = accy * corr + w0 * vA.y;
    }

    float inv = (deg > 0) ? 1.f / den : 0.f;
    float2 o2;
    o2.x = accx * inv + bias[lane * 2];
    o2.y = accy * inv + bias[lane * 2 + 1];
    *(float2*)&out[(size_t)node * DD + lane * 2] = o2;
}

// ---- lin1 over livelist rows: MFMA + GELU on input -------------------------
__global__ __launch_bounds__(256) void k_linC(const float* __restrict__ x,
                                              const unsigned short* __restrict__ wp,
                                              const float* __restrict__ b,
                                              unsigned* __restrict__ y,
                                              const int* __restrict__ livelist,
                                              const int* __restrict__ nLive) {
    int nL = *nLive;
    int wave = threadIdx.x >> 6;
    int lb = blockIdx.x * 64 + wave * 16;
    if (blockIdx.x * 64 >= nL) return;
    int lane = threadIdx.x & 63;
    int liIn = lb + (lane & 15);
    int rIn = (liIn < nL) ? livelist[liIn] : 0;

    // same as mfma_linear_rows but output rows come from livelist
    int c = lane & 15, g = lane >> 4;
    f32x4 acc[8];
    #pragma unroll
    for (int nt = 0; nt < 8; ++nt) {
        float bb = b[nt * 16 + c];
        acc[nt] = (f32x4){bb, bb, bb, bb};
    }
    const bf16x8* wv = (const bf16x8*)wp;
    for (int ks = 0; ks < 4; ++ks) {
        float xr[8];
        if (liIn < nL) {
            const float4* xp = (const float4*)&x[(size_t)rIn * DD + ks * 32 + g * 8];
            *(float4*)&xr[0] = xp[0];
            *(float4*)&xr[4] = xp[1];
            #pragma unroll
            for (int j = 0; j < 8; ++j) xr[j] = gelu1(xr[j]);
        } else {
            #pragma unroll
            for (int j = 0; j < 8; ++j) xr[j] = 0.f;
        }
        union { unsigned u[4]; bf16x8 v; } af;
        #pragma unroll
        for (int j = 0; j < 4; ++j)
            af.u[j] = bf16rne(xr[2 * j]) | (bf16rne(xr[2 * j + 1]) << 16);
        #pragma unroll
        for (int nt = 0; nt < 8; ++nt) {
            bf16x8 bv = wv[(nt * 4 + ks) * 64 + lane];
            acc[nt] = __builtin_amdgcn_mfma_f32_16x16x32_bf16(af.v, bv, acc[nt], 0, 0, 0);
        }
    }
    int g4 = g * 4;
    #pragma unroll
    for (int reg = 0; reg < 4; ++reg) {
        int liOut = lb + g4 + reg;
        int row = (liOut < nL) ? livelist[liOut] : -1;
        #pragma unroll
        for (int nt = 0; nt < 8; ++nt) {
            unsigned u = bf16rne(acc[nt][reg]);
            unsigned up = (unsigned)__shfl_xor((int)u, 1, 64);
            if (!(c & 1) && row >= 0)
                y[(size_t)row * 64 + (nt * 16 + c) / 2] = u | (up << 16);
        }
    }
}

// ---- agg1 (nodes [0,BS)) fused with linear+LayerNorm head -------------------
__global__ __launch_bounds__(256) void k_agg1head(
        const unsigned* __restrict__ xl,
        const int* __restrict__ cnt, const int* __restrict__ ssrc,
        const float* __restrict__ att, const float* __restrict__ bias,
        const float* __restrict__ wout, const float* __restrict__ bout,
        const float* __restrict__ gamma, const float* __restrict__ beta,
        float* __restrict__ yout, int N, int BS) {
    __shared__ float xrow[4][DD];
    int wid  = threadIdx.x >> 6;
    int lane = threadIdx.x & 63;
    int node = blockIdx.x * 4 + wid;
    if (node >= BS) return;
    float2 attv = *(const float2*)&att[lane * 2];
    float2 xd = bf2f(xl[(size_t)node * 64 + lane]);
    int key = N + node;
    int rs  = key * SLOT;
    int deg = cnt[key];
    deg = deg > SLOT ? SLOT : deg;

    float m = -3.4e38f, den = 0.f, accx = 0.f, accy = 0.f;
    int sA = (deg > 0) ? ssrc[rs] : 0;
    int sB = (deg > 1) ? ssrc[rs + 1] : 0;
    unsigned uA = xl[(size_t)sA * 64 + lane];
    unsigned uB = xl[(size_t)sB * 64 + lane];

    int k = 0;
    for (; k + 1 < deg; k += 2) {
        int sC = (k + 2 < deg) ? ssrc[rs + k + 2] : 0;
        int sD = (k + 3 < deg) ? ssrc[rs + k + 3] : 0;
        unsigned uC = xl[(size_t)sC * 64 + lane];
        unsigned uD = xl[(size_t)sD * 64 + lane];
        float2 vA = bf2f(uA), vB = bf2f(uB);
        float tx = xd.x + vA.x, ty = xd.y + vA.y;
        tx = tx > 0.f ? tx : 0.2f * tx;
        ty = ty > 0.f ? ty : 0.2f * ty;
        float l0 = tx * attv.x + ty * attv.y;
        tx = xd.x + vB.x; ty = xd.y + vB.y;
        tx = tx > 0.f ? tx : 0.2f * tx;
        ty = ty > 0.f ? ty : 0.2f * ty;
        float l1 = tx * attv.x + ty * attv.y;
        #pragma unroll
        for (int o = 8; o; o >>= 1) {
            l0 += __shfl_xor(l0, o, 64);
            l1 += __shfl_xor(l1, o, 64);
        }
        float mn = fmaxf(fmaxf(m, l0), l1);
        float corr = __expf(m - mn);
        float w0 = __expf(l0 - mn);
        float w1 = __expf(l1 - mn);
        den  = den  * corr + w0 + w1;
        accx = accx * corr + w0 * vA.x + w1 * vB.x;
        accy = accy * corr + w0 * vA.y + w1 * vB.y;
        m = mn;
        sA = sC; sB = sD; uA = uC; uB = uD;
    }
    if (k < deg) {
        float2 vA = bf2f(uA);
        float tx = xd.x + vA.x, ty = xd.y + vA.y;
        tx = tx > 0.f ? tx : 0.2f * tx;
        ty = ty > 0.f ? ty : 0.2f * ty;
        float l0 = tx * attv.x + ty * attv.y;
        #pragma unroll
        for (int o = 8; o; o >>= 1) l0 += __shfl_xor(l0, o, 64);
        float mn = fmaxf(m, l0);
        float corr = __expf(m - mn);
        float w0 = __expf(l0 - mn);
        den  = den  * corr + w0;
        accx = accx * corr + w0 * vA.x;
        accy = accy * corr + w0 * vA.y;
    }

    float inv = (deg > 0) ? 1.f / den : 0.f;
    float2 o2;
    o2.x = accx * inv + bias[lane * 2];
    o2.y = accy * inv + bias[lane * 2 + 1];

    xrow[wid][lane * 2]     = o2.x;
    xrow[wid][lane * 2 + 1] = o2.y;
    float2 acc2 = *(const float2*)&bout[lane * 2];
    __syncthreads();
    #pragma unroll 4
    for (int kk = 0; kk < DD; ++kk) {
        float xv = xrow[wid][kk];
        float2 wv2 = *(const float2*)&wout[(size_t)kk * DD + lane * 2];
        acc2.x += xv * wv2.x;
        acc2.y += xv * wv2.y;
    }
    float s = acc2.x + acc2.y;
    #pragma unroll
    for (int o = 32; o; o >>= 1) s += __shfl_xor(s, o, 64);
    float mean = s * (1.f / 128.f);
    float dx = acc2.x - mean, dy = acc2.y - mean;
    float s2 = dx * dx + dy * dy;
    #pragma unroll
    for (int o = 32; o; o >>= 1) s2 += __shfl_xor(s2, o, 64);
    float rstd = rsqrtf(s2 * (1.f / 128.f) + 1e-12f);
    float2 g2 = *(const float2*)&gamma[lane * 2];
    float2 b2 = *(const float2*)&beta[lane * 2];
    float2 yo;
    yo.x = dx * rstd * g2.x + b2.x;
    yo.y = dy * rstd * g2.y + b2.y;
    *(float2*)&yout[(size_t)node * DD + lane * 2] = yo;
}

extern "C" void kernel_launch(void* const* d_in, const int* in_sizes, int n_in,
                              void* d_out, int out_size, void* d_ws, size_t ws_size,
                              hipStream_t stream) {
    const float* embs  = (const float*)d_in[0];
    const float* w0    = (const float*)d_in[1];
    const float* b0    = (const float*)d_in[2];
    const float* att0  = (const float*)d_in[3];
    const float* bias0 = (const float*)d_in[4];
    const float* w1    = (const float*)d_in[5];
    const float* b1    = (const float*)d_in[6];
    const float* att1  = (const float*)d_in[7];
    const float* bias1 = (const float*)d_in[8];
    const float* wout  = (const float*)d_in[9];
    const float* bout  = (const float*)d_in[10];
    const float* gamma = (const float*)d_in[11];
    const float* beta  = (const float*)d_in[12];
    const int* ei0 = (const int*)d_in[13];
    const int* ei1 = (const int*)d_in[14];

    int N  = in_sizes[0] / DD;
    int E0 = in_sizes[13] / 2;
    int E1 = in_sizes[14] / 2;
    int BS = out_size / DD;
    int n2 = N + BS;
    int W  = (N + 31) / 32;

    // ---- workspace carve-up ----
    unsigned* xl   = (unsigned*)d_ws;                      // N*64 (bf16 pairs)
    float* out     = (float*)(xl + (size_t)N * 64);        // N*128 f32
    int* ssrc      = (int*)(out + (size_t)N * DD);         // n2*SLOT
    int* cnt       = ssrc + (size_t)n2 * SLOT;             // n2   (memset)
    unsigned* mb   = (unsigned*)(cnt + n2);                // W+32 (memset, adjacent)
    int* mex       = (int*)(mb + W + 32);                  // W
    int* mbsum     = mex + W;                              // 32
    int* livelist  = mbsum + 32;                           // N
    int* nLive     = livelist + N;                         // 1
    unsigned short* wp0 = (unsigned short*)
        (((uintptr_t)(nLive + 1) + 15) & ~(uintptr_t)15); // 16K bf16
    unsigned short* wp1 = wp0 + DD * DD;                   // 16K bf16

    int gH0  = (E0 + 1023) / 1024;
    int gH1  = (E1 + 1023) / 1024;
    int gLin = (N + 63) / 64;
    int gMs  = (W + 255) / 256;

    // 1. zero cnt + maskbits (contiguous)
    hipMemsetAsync(cnt, 0, ((size_t)n2 + W + 32) * sizeof(int), stream);
    // 2. mark live nodes (bitmask) + pack weights into B-fragment layout
    k_mark<<<gH1, 256, 0, stream>>>(ei1, ei1 + E1, E1, BS, mb, w0, w1, wp0, wp1);
    // 3. F1: MFMA linear0 || hist+fill conv0 || hist+fill conv1 || mscanA
    k_hflin<<<gLin + gH0 + gH1 + gMs, 256, 0, stream>>>(
        embs, wp0, b0, xl, N, gLin, gH0, gH1,
        ei0, ei0 + E0, E0, ei1, ei1 + E1, E1, BS,
        mb, cnt, ssrc, N, W, mex, mbsum);
    // 4. agg0 (mask-gated) with livelist-build in leading blocks
    k_aggL<<<gMs + (N + 3) / 4, 256, 0, stream>>>(
        xl, cnt, ssrc, att0, bias0, out, mb, N, gMs, W,
        mex, mbsum, livelist, nLive);
    // 5. lin1 over live rows only (MFMA, gelu on input)
    k_linC<<<gLin, 256, 0, stream>>>(out, wp1, b1, xl, livelist, nLive);
    // 6. agg1 (dst<BS) + head
    k_agg1head<<<(BS + 3) / 4, 256, 0, stream>>>(
        xl, cnt, ssrc, att1, bias1,
        wout, bout, gamma, beta, (float*)d_out, N, BS);
}